// Round 1
// baseline (80.023 us; speedup 1.0000x reference)
//
#include <hip/hip_runtime.h>
#include <math.h>

namespace {

constexpr int kL    = 2048;   // sequence length
constexpr int kWaveSz = 64;

// One wave processes one (b,l) position: computes all 768 channels
// (3 conv groups x 256), applies mask, LayerNorm over the 768 channels via
// wave shuffle reduction, writes 3 coalesced float4 per lane.
__global__ __launch_bounds__(256, 1)
void cnn_emb_ln(const int*   __restrict__ ids,     // [B*L] tokens 0..5
                const float* __restrict__ mask,    // [B*L]
                const float* __restrict__ W3,      // [256][5][3]
                const float* __restrict__ W5,      // [256][5][5]
                const float* __restrict__ W7,      // [256][5][7]
                const float* __restrict__ gamma,   // [768]
                const float* __restrict__ beta,    // [768]
                float*       __restrict__ out,     // [B*L][768]
                int npos, int total_waves)
{
    // Weights transposed to [k][c][o] so lane reads float4 at o=4*lane.
    __shared__ float sW3[3][5][256];
    __shared__ float sW5[5][5][256];
    __shared__ float sW7[7][5][256];

    const int tid = threadIdx.x;

    // Stage weights (each thread owns one output channel's rows).
    #pragma unroll
    for (int c = 0; c < 5; ++c) {
        #pragma unroll
        for (int k = 0; k < 3; ++k) sW3[k][c][tid] = W3[tid * 15 + c * 3 + k];
        #pragma unroll
        for (int k = 0; k < 5; ++k) sW5[k][c][tid] = W5[tid * 25 + c * 5 + k];
        #pragma unroll
        for (int k = 0; k < 7; ++k) sW7[k][c][tid] = W7[tid * 35 + c * 7 + k];
    }

    const int lane = tid & (kWaveSz - 1);
    const int wave = tid >> 6;

    // Per-lane gamma/beta for channels {4*lane..4*lane+3} + 256*g.
    const float4 g0 = *reinterpret_cast<const float4*>(gamma +   0 + 4 * lane);
    const float4 g1 = *reinterpret_cast<const float4*>(gamma + 256 + 4 * lane);
    const float4 g2 = *reinterpret_cast<const float4*>(gamma + 512 + 4 * lane);
    const float4 b0 = *reinterpret_cast<const float4*>(beta  +   0 + 4 * lane);
    const float4 b1 = *reinterpret_cast<const float4*>(beta  + 256 + 4 * lane);
    const float4 b2 = *reinterpret_cast<const float4*>(beta  + 512 + 4 * lane);

    __syncthreads();

    const int gwave = blockIdx.x * 4 + wave;

    for (int pos = gwave; pos < npos; pos += total_waves) {
        const int l = pos & (kL - 1);

        // Wave-uniform token classes for the 7-wide window (offset -3..+3).
        // -1 => contributes nothing (OOB or dropped padding class 5).
        int cls[7];
        #pragma unroll
        for (int j = 0; j < 7; ++j) {
            const int p = l - 3 + j;
            int c = -1;
            if (p >= 0 && p < kL) {
                c = ids[pos - 3 + j];
                if (c >= 5) c = -1;
            }
            cls[j] = c;
        }

        float4 h3 = {0.f, 0.f, 0.f, 0.f};
        float4 h5 = {0.f, 0.f, 0.f, 0.f};
        float4 h7 = {0.f, 0.f, 0.f, 0.f};

        // K=3: tap k reads window j = k+2 (offsets -1..+1)
        #pragma unroll
        for (int k = 0; k < 3; ++k) {
            const int c = cls[k + 2];
            if (c >= 0) {   // wave-uniform branch: no divergence
                const float4 w = *reinterpret_cast<const float4*>(&sW3[k][c][4 * lane]);
                h3.x += w.x; h3.y += w.y; h3.z += w.z; h3.w += w.w;
            }
        }
        // K=5: tap k reads window j = k+1 (offsets -2..+2)
        #pragma unroll
        for (int k = 0; k < 5; ++k) {
            const int c = cls[k + 1];
            if (c >= 0) {
                const float4 w = *reinterpret_cast<const float4*>(&sW5[k][c][4 * lane]);
                h5.x += w.x; h5.y += w.y; h5.z += w.z; h5.w += w.w;
            }
        }
        // K=7: tap k reads window j = k (offsets -3..+3)
        #pragma unroll
        for (int k = 0; k < 7; ++k) {
            const int c = cls[k];
            if (c >= 0) {
                const float4 w = *reinterpret_cast<const float4*>(&sW7[k][c][4 * lane]);
                h7.x += w.x; h7.y += w.y; h7.z += w.z; h7.w += w.w;
            }
        }

        const float m = mask[pos];
        h3.x *= m; h3.y *= m; h3.z *= m; h3.w *= m;
        h5.x *= m; h5.y *= m; h5.z *= m; h5.w *= m;
        h7.x *= m; h7.y *= m; h7.z *= m; h7.w *= m;

        // LayerNorm statistics over the 768 channels of this position.
        float s  = (h3.x + h3.y + h3.z + h3.w)
                 + (h5.x + h5.y + h5.z + h5.w)
                 + (h7.x + h7.y + h7.z + h7.w);
        float ss = (h3.x * h3.x + h3.y * h3.y + h3.z * h3.z + h3.w * h3.w)
                 + (h5.x * h5.x + h5.y * h5.y + h5.z * h5.z + h5.w * h5.w)
                 + (h7.x * h7.x + h7.y * h7.y + h7.z * h7.z + h7.w * h7.w);

        #pragma unroll
        for (int d = 1; d < kWaveSz; d <<= 1) {
            s  += __shfl_xor(s,  d, kWaveSz);
            ss += __shfl_xor(ss, d, kWaveSz);
        }

        const float inv_n = 1.0f / 768.0f;
        const float mu  = s * inv_n;
        const float var = fmaxf(ss * inv_n - mu * mu, 0.0f);
        const float rs  = rsqrtf(var + 1e-12f);

        float* o = out + (size_t)pos * 768;

        float4 r;
        r.x = (h3.x - mu) * rs * g0.x + b0.x;
        r.y = (h3.y - mu) * rs * g0.y + b0.y;
        r.z = (h3.z - mu) * rs * g0.z + b0.z;
        r.w = (h3.w - mu) * rs * g0.w + b0.w;
        *reinterpret_cast<float4*>(o +   0 + 4 * lane) = r;

        r.x = (h5.x - mu) * rs * g1.x + b1.x;
        r.y = (h5.y - mu) * rs * g1.y + b1.y;
        r.z = (h5.z - mu) * rs * g1.z + b1.z;
        r.w = (h5.w - mu) * rs * g1.w + b1.w;
        *reinterpret_cast<float4*>(o + 256 + 4 * lane) = r;

        r.x = (h7.x - mu) * rs * g2.x + b2.x;
        r.y = (h7.y - mu) * rs * g2.y + b2.y;
        r.z = (h7.z - mu) * rs * g2.z + b2.z;
        r.w = (h7.w - mu) * rs * g2.w + b2.w;
        *reinterpret_cast<float4*>(o + 512 + 4 * lane) = r;
    }
}

} // namespace

extern "C" void kernel_launch(void* const* d_in, const int* in_sizes, int n_in,
                              void* d_out, int out_size, void* d_ws, size_t ws_size,
                              hipStream_t stream) {
    const int*   ids   = (const int*)  d_in[0];
    const float* mask  = (const float*)d_in[1];
    const float* W3    = (const float*)d_in[2];
    const float* W5    = (const float*)d_in[3];
    const float* W7    = (const float*)d_in[4];
    const float* gamma = (const float*)d_in[5];
    const float* beta  = (const float*)d_in[6];
    float*       out   = (float*)d_out;

    const int npos = in_sizes[0];          // B*L = 65536
    const int grid = 512;                  // 2 blocks/CU (75 KiB LDS each)
    const int total_waves = grid * 4;      // 4 waves per 256-thread block

    hipLaunchKernelGGL(cnn_emb_ln, dim3(grid), dim3(256), 0, stream,
                       ids, mask, W3, W5, W7, gamma, beta, out,
                       npos, total_waves);
}

// Round 3
// 59.677 us; speedup vs baseline: 1.3409x; 1.3409x over previous
//
#include <hip/hip_runtime.h>
#include <math.h>

namespace {

constexpr int kL      = 2048;  // sequence length
constexpr int kWaveSz = 64;
constexpr int kBlkPos = 128;   // positions per block (divides kL)
constexpr int kThreads = 512;  // 8 waves; wave w owns positions [w*16, w*16+16)

typedef float vfloat4 __attribute__((ext_vector_type(4)));  // for nontemporal stores

// One wave per position: 768 channels = 3 groups x 256; lane owns 4 channels
// per group. Weights staged to LDS as [k][class][channel] so a lane's float4
// read at o=4*lane is a conflict-free ds_read_b128. Token classes for the
// block's 128-position span (+3 halo each side) precomputed once into LDS.
__global__ __launch_bounds__(kThreads, 4)
void cnn_emb_ln(const int*   __restrict__ ids,     // [B*L] tokens 0..5
                const float* __restrict__ mask,    // [B*L]
                const float* __restrict__ W3,      // [256][5][3]
                const float* __restrict__ W5,      // [256][5][5]
                const float* __restrict__ W7,      // [256][5][7]
                const float* __restrict__ gamma,   // [768]
                const float* __restrict__ beta,    // [768]
                float*       __restrict__ out)     // [B*L][768]
{
    __shared__ float sW3[3][5][256];
    __shared__ float sW5[5][5][256];
    __shared__ float sW7[7][5][256];
    __shared__ int   scls[kBlkPos + 6];   // class per position, -1 = no contribution
    __shared__ float smask[kBlkPos];

    const int tid = threadIdx.x;
    const int block_base = blockIdx.x * kBlkPos;          // within one sequence
    const int seq_base   = block_base & ~(kL - 1);

    // ---- stage weights, transposed to [k][c][o] ----
    for (int i = tid; i < 3 * 5 * 256; i += kThreads) {
        const int k = i / (5 * 256), c = (i / 256) % 5, o = i & 255;
        sW3[k][c][o] = W3[o * 15 + c * 3 + k];
    }
    for (int i = tid; i < 5 * 5 * 256; i += kThreads) {
        const int k = i / (5 * 256), c = (i / 256) % 5, o = i & 255;
        sW5[k][c][o] = W5[o * 25 + c * 5 + k];
    }
    for (int i = tid; i < 7 * 5 * 256; i += kThreads) {
        const int k = i / (5 * 256), c = (i / 256) % 5, o = i & 255;
        sW7[k][c][o] = W7[o * 35 + c * 7 + k];
    }

    // ---- stage token classes (with halo) and mask ----
    if (tid < kBlkPos + 6) {
        const int p = block_base - 3 + tid;
        int c = -1;
        if (p >= seq_base && p < seq_base + kL) {
            c = ids[p];
            if (c >= 5) c = -1;               // dropped padding class
        }
        scls[tid] = c;
    }
    if (tid < kBlkPos) smask[tid] = mask[block_base + tid];

    const int lane = tid & (kWaveSz - 1);
    const int wave = tid >> 6;

    // per-lane gamma/beta for channels {4*lane..4*lane+3} + 256*g
    const float4 g0 = *reinterpret_cast<const float4*>(gamma +   0 + 4 * lane);
    const float4 g1 = *reinterpret_cast<const float4*>(gamma + 256 + 4 * lane);
    const float4 g2 = *reinterpret_cast<const float4*>(gamma + 512 + 4 * lane);
    const float4 b0 = *reinterpret_cast<const float4*>(beta  +   0 + 4 * lane);
    const float4 b1 = *reinterpret_cast<const float4*>(beta  + 256 + 4 * lane);
    const float4 b2 = *reinterpret_cast<const float4*>(beta  + 512 + 4 * lane);

    __syncthreads();

    const int wloc = wave * 16;               // this wave's local position base

    for (int i = 0; i < 16; ++i) {
        const int li = wloc + i;              // local position in block

        // wave-uniform window classes: broadcast LDS reads
        int cls[7];
        #pragma unroll
        for (int j = 0; j < 7; ++j) cls[j] = scls[li + j];
        const float m = smask[li];

        float4 h3 = {0.f, 0.f, 0.f, 0.f};
        float4 h5 = {0.f, 0.f, 0.f, 0.f};
        float4 h7 = {0.f, 0.f, 0.f, 0.f};

        #pragma unroll
        for (int k = 0; k < 3; ++k) {         // K=3: window j = k+2
            const int c = cls[k + 2];
            if (c >= 0) {                     // wave-uniform branch
                const float4 w = *reinterpret_cast<const float4*>(&sW3[k][c][4 * lane]);
                h3.x += w.x; h3.y += w.y; h3.z += w.z; h3.w += w.w;
            }
        }
        #pragma unroll
        for (int k = 0; k < 5; ++k) {         // K=5: window j = k+1
            const int c = cls[k + 1];
            if (c >= 0) {
                const float4 w = *reinterpret_cast<const float4*>(&sW5[k][c][4 * lane]);
                h5.x += w.x; h5.y += w.y; h5.z += w.z; h5.w += w.w;
            }
        }
        #pragma unroll
        for (int k = 0; k < 7; ++k) {         // K=7: window j = k
            const int c = cls[k];
            if (c >= 0) {
                const float4 w = *reinterpret_cast<const float4*>(&sW7[k][c][4 * lane]);
                h7.x += w.x; h7.y += w.y; h7.z += w.z; h7.w += w.w;
            }
        }

        h3.x *= m; h3.y *= m; h3.z *= m; h3.w *= m;
        h5.x *= m; h5.y *= m; h5.z *= m; h5.w *= m;
        h7.x *= m; h7.y *= m; h7.z *= m; h7.w *= m;

        // LayerNorm stats over 768 channels: 64-lane butterfly
        float s  = (h3.x + h3.y + h3.z + h3.w)
                 + (h5.x + h5.y + h5.z + h5.w)
                 + (h7.x + h7.y + h7.z + h7.w);
        float ss = (h3.x * h3.x + h3.y * h3.y + h3.z * h3.z + h3.w * h3.w)
                 + (h5.x * h5.x + h5.y * h5.y + h5.z * h5.z + h5.w * h5.w)
                 + (h7.x * h7.x + h7.y * h7.y + h7.z * h7.z + h7.w * h7.w);
        #pragma unroll
        for (int d = 1; d < kWaveSz; d <<= 1) {
            s  += __shfl_xor(s,  d, kWaveSz);
            ss += __shfl_xor(ss, d, kWaveSz);
        }

        const float inv_n = 1.0f / 768.0f;
        const float mu  = s * inv_n;
        const float var = fmaxf(ss * inv_n - mu * mu, 0.0f);
        const float rs  = rsqrtf(var + 1e-12f);

        float* o = out + (size_t)(block_base + li) * 768;

        vfloat4 r;
        r.x = (h3.x - mu) * rs * g0.x + b0.x;
        r.y = (h3.y - mu) * rs * g0.y + b0.y;
        r.z = (h3.z - mu) * rs * g0.z + b0.z;
        r.w = (h3.w - mu) * rs * g0.w + b0.w;
        __builtin_nontemporal_store(r, reinterpret_cast<vfloat4*>(o + 0 + 4 * lane));

        r.x = (h5.x - mu) * rs * g1.x + b1.x;
        r.y = (h5.y - mu) * rs * g1.y + b1.y;
        r.z = (h5.z - mu) * rs * g1.z + b1.z;
        r.w = (h5.w - mu) * rs * g1.w + b1.w;
        __builtin_nontemporal_store(r, reinterpret_cast<vfloat4*>(o + 256 + 4 * lane));

        r.x = (h7.x - mu) * rs * g2.x + b2.x;
        r.y = (h7.y - mu) * rs * g2.y + b2.y;
        r.z = (h7.z - mu) * rs * g2.z + b2.z;
        r.w = (h7.w - mu) * rs * g2.w + b2.w;
        __builtin_nontemporal_store(r, reinterpret_cast<vfloat4*>(o + 512 + 4 * lane));
    }
}

} // namespace

extern "C" void kernel_launch(void* const* d_in, const int* in_sizes, int n_in,
                              void* d_out, int out_size, void* d_ws, size_t ws_size,
                              hipStream_t stream) {
    const int*   ids   = (const int*)  d_in[0];
    const float* mask  = (const float*)d_in[1];
    const float* W3    = (const float*)d_in[2];
    const float* W5    = (const float*)d_in[3];
    const float* W7    = (const float*)d_in[4];
    const float* gamma = (const float*)d_in[5];
    const float* beta  = (const float*)d_in[6];
    float*       out   = (float*)d_out;

    const int npos = in_sizes[0];              // B*L = 65536
    const int grid = npos / kBlkPos;           // 512 blocks, 2/CU (LDS ~76 KiB)

    hipLaunchKernelGGL(cnn_emb_ln, dim3(grid), dim3(kThreads), 0, stream,
                       ids, mask, W3, W5, W7, gamma, beta, out);
}